// Round 1
// baseline (329.021 us; speedup 1.0000x reference)
//
#include <hip/hip_runtime.h>
#include <hip/hip_bf16.h>
#include <math.h>

// LBGC: log-sigmoid TransR scoring.
// pos[b]  = softplus(-s_b),  s = dot(P_t u + time_t, poi_p)
// neg[ns] = sum_b softplus(+s_{ns,b})
//
// Strategy: sort samples by t (168 bins) -> block stages P_t in LDS ->
// each wave batches 4 samples, poi row consumed via wave-uniform scalar loads.

#define CPB 8  // chunks (blocks) per t-bin

__device__ __forceinline__ float softplusf(float x) {
    return fmaxf(x, 0.f) + log1pf(expf(-fabsf(x)));
}

// ---------------- zero counts ----------------
__global__ void k_zero(int* __restrict__ counts, int T) {
    int i = threadIdx.x;
    if (i < T) counts[i] = 0;
}

// ---------------- histogram over t ----------------
__global__ void k_hist(const int* __restrict__ pos_t, const int* __restrict__ neg_t,
                       int* __restrict__ counts, int B, int total) {
    int s = blockIdx.x * blockDim.x + threadIdx.x;
    if (s >= total) return;
    int t = (s < B) ? pos_t[s] : neg_t[s - B];
    atomicAdd(counts + t, 1);
}

// ---------------- exclusive scan (T <= 256, single block) ----------------
__global__ void k_scan(const int* __restrict__ counts, int* __restrict__ offsets,
                       int* __restrict__ cursor, int T) {
    __shared__ int tmp[256];
    int tid = threadIdx.x;
    int c = (tid < T) ? counts[tid] : 0;
    tmp[tid] = c;
    __syncthreads();
    for (int d = 1; d < 256; d <<= 1) {
        int v = (tid >= d) ? tmp[tid - d] : 0;
        __syncthreads();
        tmp[tid] += v;
        __syncthreads();
    }
    if (tid < T) {
        int excl = tmp[tid] - c;
        offsets[tid] = excl;
        cursor[tid]  = excl;
        if (tid == T - 1) offsets[T] = tmp[tid];
    }
}

// ---------------- scatter sample ids into bins ----------------
__global__ void k_scatter(const int* __restrict__ pos_t, const int* __restrict__ neg_t,
                          int* __restrict__ cursor, int* __restrict__ sorted,
                          int B, int total) {
    int s = blockIdx.x * blockDim.x + threadIdx.x;
    if (s >= total) return;
    int t = (s < B) ? pos_t[s] : neg_t[s - B];
    int p = atomicAdd(cursor + t, 1);
    sorted[p] = s;
}

// ---------------- main scoring kernel ----------------
__global__ __launch_bounds__(256) void k_main(
    const int* __restrict__ pos_u, const int* __restrict__ pos_p,
    const int* __restrict__ neg_u, const int* __restrict__ neg_p,
    const float* __restrict__ user_emb, const float* __restrict__ poi_emb,
    const float* __restrict__ time_emb, const float* __restrict__ proj_emb,
    const int* __restrict__ offsets, const int* __restrict__ sorted,
    float* __restrict__ out, float* __restrict__ negpart,
    int B, int shiftB, int G4, int NS)
{
    __shared__ float ldsP[128 * 128];  // exactly 64 KiB

    const int t     = blockIdx.x / CPB;
    const int chunk = blockIdx.x % CPB;
    const int off   = offsets[t];
    const int end   = offsets[t + 1];
    const int tid   = threadIdx.x;
    const int wave  = tid >> 6;
    const int lane  = tid & 63;

    float nacc = 0.f;  // this thread's neg accumulator (lane == ns owns ns)

    const bool has = (off + chunk) < end;  // block-uniform
    if (has) {
        // ---- stage P_t into LDS (coalesced float4) ----
        const float4* Pg = (const float4*)(proj_emb + (size_t)t * 16384);
        float4* Pl = (float4*)ldsP;
        #pragma unroll
        for (int k = 0; k < 16; ++k) Pl[tid + 256 * k] = Pg[tid + 256 * k];
        __syncthreads();

        const float2 tt = *(const float2*)(time_emb + (size_t)t * 128 + 2 * lane);

        // wave-strided passes of 4 samples each over this block's slice
        for (int jb = wave * 4; off + chunk + jb * CPB < end; jb += 16) {
            int  sid[4], uq[4], pq[4];
            bool act[4];
            #pragma unroll
            for (int k = 0; k < 4; ++k) {
                int p = off + chunk + (jb + k) * CPB;
                act[k] = (p < end);
                int pp = act[k] ? p : (off + chunk);
                int s = __builtin_amdgcn_readfirstlane(sorted[pp]);
                int u_, p_;
                if (s < B) { u_ = pos_u[s]; p_ = pos_p[s]; }
                else       { int r = s - B; u_ = neg_u[r]; p_ = neg_p[r]; }
                sid[k] = s;
                uq[k] = __builtin_amdgcn_readfirstlane(u_);
                pq[k] = __builtin_amdgcn_readfirstlane(p_);
            }

            // gather u and poi rows (coalesced 512B per wave per row)
            float2 u2[4];
            float  tp[4];
            const float* poiS[4];
            #pragma unroll
            for (int k = 0; k < 4; ++k) {
                u2[k] = *(const float2*)(user_emb + (size_t)uq[k] * 128 + 2 * lane);
                float2 p2 = *(const float2*)(poi_emb + (size_t)pq[k] * 128 + 2 * lane);
                tp[k] = tt.x * p2.x + tt.y * p2.y;   // per-lane share of dot(time, poi)
                poiS[k] = poi_emb + (size_t)pq[k] * 128;  // uniform base -> s_load
            }

            // w[j] = sum_i P[i][j] * poi[i]; lane owns j = 2*lane, 2*lane+1
            float w0[4] = {0, 0, 0, 0}, w1[4] = {0, 0, 0, 0};
            #pragma unroll 8
            for (int i = 0; i < 128; ++i) {
                float2 a = *(const float2*)(ldsP + i * 128 + 2 * lane);
                #pragma unroll
                for (int k = 0; k < 4; ++k) {
                    float ps = poiS[k][i];  // wave-uniform scalar (SGPR operand)
                    w0[k] = fmaf(a.x, ps, w0[k]);
                    w1[k] = fmaf(a.y, ps, w1[k]);
                }
            }

            #pragma unroll
            for (int k = 0; k < 4; ++k) {
                float part = fmaf(u2[k].x, w0[k], fmaf(u2[k].y, w1[k], tp[k]));
                #pragma unroll
                for (int m = 32; m > 0; m >>= 1) part += __shfl_xor(part, m, 64);
                if (act[k]) {
                    int s = sid[k];
                    if (s < B) {
                        if (lane == 0) out[s] = softplusf(-part);
                    } else {
                        int nsk = (s - B) >> shiftB;
                        if (lane == nsk) nacc += softplusf(part);
                    }
                }
            }
        }
    }

    // every wave (even empty blocks) writes its NS partials: ws is poisoned
    int gw = blockIdx.x * 4 + wave;
    if (lane < NS) negpart[(size_t)lane * G4 + gw] = nacc;
}

// ---------------- final neg reduction ----------------
__global__ void k_reduce(const float* __restrict__ negpart, float* __restrict__ out,
                         int B, int NS, int G4) {
    __shared__ float red[256];
    for (int ns = 0; ns < NS; ++ns) {
        float acc = 0.f;
        for (int r = threadIdx.x; r < G4; r += blockDim.x)
            acc += negpart[(size_t)ns * G4 + r];
        red[threadIdx.x] = acc;
        __syncthreads();
        for (int s = 128; s > 0; s >>= 1) {
            if (threadIdx.x < s) red[threadIdx.x] += red[threadIdx.x + s];
            __syncthreads();
        }
        if (threadIdx.x == 0) out[B + ns] = red[0];
        __syncthreads();
    }
}

extern "C" void kernel_launch(void* const* d_in, const int* in_sizes, int n_in,
                              void* d_out, int out_size, void* d_ws, size_t ws_size,
                              hipStream_t stream) {
    const int*   pos_u    = (const int*)d_in[0];
    const int*   pos_t    = (const int*)d_in[1];
    const int*   pos_p    = (const int*)d_in[2];
    const int*   neg_u    = (const int*)d_in[3];
    const int*   neg_t    = (const int*)d_in[4];
    const int*   neg_p    = (const int*)d_in[5];
    const float* user_emb = (const float*)d_in[7];
    const float* poi_emb  = (const float*)d_in[8];
    const float* time_emb = (const float*)d_in[9];
    const float* proj_emb = (const float*)d_in[10];
    float* out = (float*)d_out;

    const int B     = in_sizes[0];           // 4096
    const int NS    = in_sizes[3] / B;       // 10
    const int total = B + NS * B;            // 45056
    const int T     = in_sizes[9] / 128;     // 168 time slots

    int shiftB = 0;
    while ((1 << shiftB) < B) shiftB++;      // B is 4096 (pow2)

    // workspace layout (ints then floats)
    int* ws_i    = (int*)d_ws;
    int* counts  = ws_i;                     // [T]
    int* offsets = ws_i + T;                 // [T+1]
    int* cursor  = ws_i + 2 * T + 1;         // [T]
    int* sorted  = ws_i + 3 * T + 2;         // [total]
    const int gridMain = T * CPB;
    const int G4 = gridMain * 4;             // wave rows in negpart
    float* negpart = (float*)(ws_i + 3 * T + 2 + total);  // [NS][G4]

    const int blocks = (total + 255) / 256;

    k_zero<<<1, 256, 0, stream>>>(counts, T);
    k_hist<<<blocks, 256, 0, stream>>>(pos_t, neg_t, counts, B, total);
    k_scan<<<1, 256, 0, stream>>>(counts, offsets, cursor, T);
    k_scatter<<<blocks, 256, 0, stream>>>(pos_t, neg_t, cursor, sorted, B, total);
    k_main<<<gridMain, 256, 0, stream>>>(pos_u, pos_p, neg_u, neg_p,
                                         user_emb, poi_emb, time_emb, proj_emb,
                                         offsets, sorted, out, negpart,
                                         B, shiftB, G4, NS);
    k_reduce<<<1, 256, 0, stream>>>(negpart, out, B, NS, G4);
}

// Round 2
// 223.533 us; speedup vs baseline: 1.4719x; 1.4719x over previous
//
#include <hip/hip_runtime.h>
#include <hip/hip_bf16.h>
#include <math.h>

// LBGC: log-sigmoid TransR scoring.
// pos[b]  = softplus(-s_b),  s = dot(P_t u + time_t, poi_p)
// neg[ns] = sum_b softplus(+s_{ns,b})
//
// Pipeline: memset counts -> LDS-aggregated hist -> scan -> LDS-ranked
// scatter -> main (P_t staged in LDS, 8-sample batches per wave, poi
// broadcast via v_readlane from registers) -> per-ns reduce.

#define CPB   4   // blocks (chunks) per t-bin
#define WAVES 8   // 512-thread blocks
#define BATCH 8   // samples per wave per pass

__device__ __forceinline__ float softplusf(float x) {
    return fmaxf(x, 0.f) + log1pf(expf(-fabsf(x)));
}

__device__ __forceinline__ float rdlane(float v, int l) {
    return __int_as_float(__builtin_amdgcn_readlane(__float_as_int(v), l));
}

// ---------------- histogram over t (LDS-aggregated) ----------------
__global__ void k_hist(const int* __restrict__ pos_t, const int* __restrict__ neg_t,
                       int* __restrict__ counts, int B, int total, int T) {
    __shared__ int h[256];
    h[threadIdx.x] = 0;
    __syncthreads();
    int s = blockIdx.x * blockDim.x + threadIdx.x;
    if (s < total) {
        int t = (s < B) ? pos_t[s] : neg_t[s - B];
        atomicAdd(&h[t], 1);
    }
    __syncthreads();
    if (threadIdx.x < T && h[threadIdx.x])
        atomicAdd(counts + threadIdx.x, h[threadIdx.x]);
}

// ---------------- exclusive scan (T <= 256, single block) ----------------
__global__ void k_scan(const int* __restrict__ counts, int* __restrict__ offsets,
                       int* __restrict__ cursor, int T) {
    __shared__ int tmp[256];
    int tid = threadIdx.x;
    int c = (tid < T) ? counts[tid] : 0;
    tmp[tid] = c;
    __syncthreads();
    for (int d = 1; d < 256; d <<= 1) {
        int v = (tid >= d) ? tmp[tid - d] : 0;
        __syncthreads();
        tmp[tid] += v;
        __syncthreads();
    }
    if (tid < T) {
        int excl = tmp[tid] - c;
        offsets[tid] = excl;
        cursor[tid]  = excl;
        if (tid == T - 1) offsets[T] = tmp[tid];
    }
}

// ---------------- scatter sample ids into bins (LDS-ranked) ----------------
__global__ void k_scatter(const int* __restrict__ pos_t, const int* __restrict__ neg_t,
                          int* __restrict__ cursor, int* __restrict__ sorted,
                          int B, int total, int T) {
    __shared__ int h[256];
    __shared__ int base[256];
    h[threadIdx.x] = 0;
    __syncthreads();
    int s = blockIdx.x * blockDim.x + threadIdx.x;
    int t = 0, r = 0;
    bool act = (s < total);
    if (act) {
        t = (s < B) ? pos_t[s] : neg_t[s - B];
        r = atomicAdd(&h[t], 1);
    }
    __syncthreads();
    if (threadIdx.x < T && h[threadIdx.x])
        base[threadIdx.x] = atomicAdd(cursor + threadIdx.x, h[threadIdx.x]);
    __syncthreads();
    if (act) sorted[base[t] + r] = s;
}

// ---------------- main scoring kernel ----------------
__global__ __launch_bounds__(512) void k_main(
    const int* __restrict__ pos_u, const int* __restrict__ pos_p,
    const int* __restrict__ neg_u, const int* __restrict__ neg_p,
    const float* __restrict__ user_emb, const float* __restrict__ poi_emb,
    const float* __restrict__ time_emb, const float* __restrict__ proj_emb,
    const int* __restrict__ offsets, const int* __restrict__ sorted,
    float* __restrict__ out, float* __restrict__ negpart,
    int B, int shiftB, int GW, int NS)
{
    __shared__ float ldsP[128 * 128];  // 64 KiB

    const int t     = blockIdx.x / CPB;
    const int chunk = blockIdx.x % CPB;
    const int off   = offsets[t];
    const int end   = offsets[t + 1];
    const int tid   = threadIdx.x;
    const int wave  = tid >> 6;
    const int lane  = tid & 63;

    float nacc = 0.f;  // lane == ns owns ns partial

    const bool has = (off + chunk) < end;  // block-uniform
    if (has) {
        // ---- stage P_t into LDS (coalesced float4, 512 threads x 8) ----
        const float4* Pg = (const float4*)(proj_emb + (size_t)t * 16384);
        float4* Pl = (float4*)ldsP;
        #pragma unroll
        for (int k = 0; k < 8; ++k) Pl[tid + 512 * k] = Pg[tid + 512 * k];
        __syncthreads();

        const float2 tt = *(const float2*)(time_emb + (size_t)t * 128 + 2 * lane);

        for (int jb = wave * BATCH; off + chunk + jb * CPB < end; jb += WAVES * BATCH) {
            int  sid[BATCH];
            bool act[BATCH];
            float px[BATCH], py[BATCH], tp[BATCH];
            float2 u2[BATCH];
            #pragma unroll
            for (int k = 0; k < BATCH; ++k) {
                int p = off + chunk + (jb + k) * CPB;
                act[k] = (p < end);
                int pp = act[k] ? p : (off + chunk);
                int s = __builtin_amdgcn_readfirstlane(sorted[pp]);
                int u_, p_;
                if (s < B) { u_ = pos_u[s]; p_ = pos_p[s]; }
                else       { int r = s - B; u_ = neg_u[r]; p_ = neg_p[r]; }
                sid[k] = s;
                int uq = __builtin_amdgcn_readfirstlane(u_);
                int pq = __builtin_amdgcn_readfirstlane(p_);
                u2[k] = *(const float2*)(user_emb + (size_t)uq * 128 + 2 * lane);
                float2 p2 = *(const float2*)(poi_emb + (size_t)pq * 128 + 2 * lane);
                px[k] = p2.x;
                py[k] = p2.y;
                tp[k] = tt.x * p2.x + tt.y * p2.y;  // per-lane share of dot(time, poi)
            }

            // w[j] = sum_i P[i][j] * poi[i]; lane owns j = 2*lane, 2*lane+1.
            // poi[i] broadcast from registers: lane i/2 holds (poi[2i'],poi[2i'+1]).
            float w0[BATCH], w1[BATCH];
            #pragma unroll
            for (int k = 0; k < BATCH; ++k) { w0[k] = 0.f; w1[k] = 0.f; }
            #pragma unroll 2
            for (int i = 0; i < 128; i += 2) {
                float2 a0 = *(const float2*)(ldsP + i * 128 + 2 * lane);
                float2 a1 = *(const float2*)(ldsP + (i + 1) * 128 + 2 * lane);
                #pragma unroll
                for (int k = 0; k < BATCH; ++k) {
                    float s0 = rdlane(px[k], i >> 1);
                    float s1 = rdlane(py[k], i >> 1);
                    w0[k] = fmaf(a0.x, s0, w0[k]);
                    w1[k] = fmaf(a0.y, s0, w1[k]);
                    w0[k] = fmaf(a1.x, s1, w0[k]);
                    w1[k] = fmaf(a1.y, s1, w1[k]);
                }
            }

            #pragma unroll
            for (int k = 0; k < BATCH; ++k) {
                float part = fmaf(u2[k].x, w0[k], fmaf(u2[k].y, w1[k], tp[k]));
                #pragma unroll
                for (int m = 32; m > 0; m >>= 1) part += __shfl_xor(part, m, 64);
                if (act[k]) {
                    int s = sid[k];
                    if (s < B) {
                        if (lane == 0) out[s] = softplusf(-part);
                    } else {
                        int nsk = (s - B) >> shiftB;
                        if (lane == nsk) nacc += softplusf(part);
                    }
                }
            }
        }
    }

    // every wave (even empty blocks) writes its NS partials: ws is poisoned
    int gw = blockIdx.x * WAVES + wave;
    if (lane < NS) negpart[(size_t)lane * GW + gw] = nacc;
}

// ---------------- final neg reduction (one block per ns) ----------------
__global__ void k_reduce(const float* __restrict__ negpart, float* __restrict__ out,
                         int B, int GW) {
    __shared__ float red[256];
    int ns = blockIdx.x;
    float acc = 0.f;
    for (int r = threadIdx.x; r < GW; r += 256)
        acc += negpart[(size_t)ns * GW + r];
    red[threadIdx.x] = acc;
    __syncthreads();
    for (int s = 128; s > 0; s >>= 1) {
        if (threadIdx.x < s) red[threadIdx.x] += red[threadIdx.x + s];
        __syncthreads();
    }
    if (threadIdx.x == 0) out[B + ns] = red[0];
}

extern "C" void kernel_launch(void* const* d_in, const int* in_sizes, int n_in,
                              void* d_out, int out_size, void* d_ws, size_t ws_size,
                              hipStream_t stream) {
    const int*   pos_u    = (const int*)d_in[0];
    const int*   pos_t    = (const int*)d_in[1];
    const int*   pos_p    = (const int*)d_in[2];
    const int*   neg_u    = (const int*)d_in[3];
    const int*   neg_t    = (const int*)d_in[4];
    const int*   neg_p    = (const int*)d_in[5];
    const float* user_emb = (const float*)d_in[7];
    const float* poi_emb  = (const float*)d_in[8];
    const float* time_emb = (const float*)d_in[9];
    const float* proj_emb = (const float*)d_in[10];
    float* out = (float*)d_out;

    const int B     = in_sizes[0];           // 4096
    const int NS    = in_sizes[3] / B;       // 10
    const int total = B + NS * B;            // 45056
    const int T     = in_sizes[9] / 128;     // 168 time slots

    int shiftB = 0;
    while ((1 << shiftB) < B) shiftB++;      // B = 4096 (pow2)

    // workspace layout (ints then floats)
    int* ws_i    = (int*)d_ws;
    int* counts  = ws_i;                     // [T]
    int* offsets = ws_i + T;                 // [T+1]
    int* cursor  = ws_i + 2 * T + 1;         // [T]
    int* sorted  = ws_i + 3 * T + 2;         // [total]
    const int gridMain = T * CPB;
    const int GW = gridMain * WAVES;         // wave rows in negpart
    float* negpart = (float*)(ws_i + 3 * T + 2 + total);  // [NS][GW]

    const int blocks = (total + 255) / 256;

    hipMemsetAsync(counts, 0, T * sizeof(int), stream);
    k_hist<<<blocks, 256, 0, stream>>>(pos_t, neg_t, counts, B, total, T);
    k_scan<<<1, 256, 0, stream>>>(counts, offsets, cursor, T);
    k_scatter<<<blocks, 256, 0, stream>>>(pos_t, neg_t, cursor, sorted, B, total, T);
    k_main<<<gridMain, 512, 0, stream>>>(pos_u, pos_p, neg_u, neg_p,
                                         user_emb, poi_emb, time_emb, proj_emb,
                                         offsets, sorted, out, negpart,
                                         B, shiftB, GW, NS);
    k_reduce<<<NS, 256, 0, stream>>>(negpart, out, B, GW);
}

// Round 3
// 182.427 us; speedup vs baseline: 1.8036x; 1.2253x over previous
//
#include <hip/hip_runtime.h>
#include <hip/hip_bf16.h>
#include <math.h>

// LBGC: log-sigmoid TransR scoring.
// pos[b]  = softplus(-s_b),  s = dot(P_t u + time_t, poi_p)
// neg[ns] = sum_b softplus(+s_{ns,b})
//
// Pipeline (no global atomics anywhere):
//   k1: per-block histograms over t  -> hcnt[T][NB]   (direct stores)
//   k2: bin offsets + per-block scatter bases (1 block)
//   k3: scatter sample ids into t-sorted order (LDS cursors)
//   k_main: per t-bin, stage P_t as bf16 in LDS (XOR-swizzled); each wave
//           scores 16 samples via 32x mfma_f32_16x16x32_bf16 (V = P*U),
//           epilogue dot with poi + time in fp32.
//   k_reduce: sum per-block neg partials.

typedef __attribute__((ext_vector_type(8))) short bfx8;
typedef __attribute__((ext_vector_type(4))) float f32x4;

#define CPB  4    // chunks (blocks) per t-bin
#define NTHR 256  // 4 waves per block

__device__ __forceinline__ float softplusf(float x) {
    return fmaxf(x, 0.f) + log1pf(expf(-fabsf(x)));
}

// f32 -> bf16 bits, round-to-nearest-even
__device__ __forceinline__ unsigned short f2bf(float f) {
    unsigned u = __float_as_uint(f);
    unsigned r = u + 0x7FFFu + ((u >> 16) & 1u);
    return (unsigned short)(r >> 16);
}

// ---------------- k1: per-block histogram (no global atomics) ----------------
__global__ void k1_hist(const int* __restrict__ pos_t, const int* __restrict__ neg_t,
                        int* __restrict__ hcnt, int B, int total, int T, int NB) {
    __shared__ int h[256];
    int tid = threadIdx.x;
    if (tid < 256) h[tid] = 0;
    __syncthreads();
    int s = blockIdx.x * blockDim.x + tid;
    if (s < total) {
        int t = (s < B) ? pos_t[s] : neg_t[s - B];
        atomicAdd(&h[t], 1);
    }
    __syncthreads();
    if (tid < T) hcnt[tid * NB + blockIdx.x] = h[tid];
}

// ---------------- k2: offsets + per-block bases (1 block, 256 thr) ----------------
__global__ void k2_scan(const int* __restrict__ hcnt, int* __restrict__ cbase,
                        int* __restrict__ offsets, int T, int NB) {
    __shared__ int tmp[256];
    int tid = threadIdx.x;
    int c = 0;
    if (tid < T)
        for (int b = 0; b < NB; ++b) c += hcnt[tid * NB + b];
    tmp[tid] = c;
    __syncthreads();
    for (int d = 1; d < 256; d <<= 1) {
        int v = (tid >= d) ? tmp[tid - d] : 0;
        __syncthreads();
        tmp[tid] += v;
        __syncthreads();
    }
    if (tid < T) {
        int run = tmp[tid] - c;  // exclusive prefix
        offsets[tid] = run;
        for (int b = 0; b < NB; ++b) { cbase[tid * NB + b] = run; run += hcnt[tid * NB + b]; }
        if (tid == T - 1) offsets[T] = tmp[tid];
    }
}

// ---------------- k3: scatter (LDS cursors, no global atomics) ----------------
__global__ void k3_scatter(const int* __restrict__ pos_t, const int* __restrict__ neg_t,
                           const int* __restrict__ cbase, int* __restrict__ sorted,
                           int B, int total, int T, int NB) {
    __shared__ int cur[256];
    int tid = threadIdx.x;
    if (tid < T) cur[tid] = cbase[tid * NB + blockIdx.x];
    __syncthreads();
    int s = blockIdx.x * blockDim.x + tid;
    if (s < total) {
        int t = (s < B) ? pos_t[s] : neg_t[s - B];
        int r = atomicAdd(&cur[t], 1);
        sorted[r] = s;
    }
}

// ---------------- main scoring kernel (MFMA) ----------------
__global__ __launch_bounds__(NTHR) void k_main(
    const int* __restrict__ pos_u, const int* __restrict__ pos_p,
    const int* __restrict__ neg_u, const int* __restrict__ neg_p,
    const float* __restrict__ user_emb, const float* __restrict__ poi_emb,
    const float* __restrict__ time_emb, const float* __restrict__ proj_emb,
    const int* __restrict__ offsets, const int* __restrict__ sorted,
    float* __restrict__ out, float* __restrict__ negpart,
    int B, int shiftB, int NS, int gridN)
{
    __shared__ __align__(16) unsigned short ldsP[128 * 128];  // bf16 bits, 32 KiB
    __shared__ __align__(16) float ldsT[128];
    __shared__ float ldsNeg[4 * 16];

    const int t     = blockIdx.x / CPB;
    const int chunk = blockIdx.x % CPB;
    const int off   = offsets[t];
    const int end   = offsets[t + 1];
    const int tid   = threadIdx.x;
    const int wave  = tid >> 6;
    const int lane  = tid & 63;
    const int q     = lane >> 4;   // quad 0..3
    const int n     = lane & 15;   // sample slot / A-row within tile

    if (tid < 64) ldsNeg[tid] = 0.f;

    const bool has = (off + chunk * 16) < end;  // block-uniform
    if (has) {
        // stage P_t as bf16, XOR-swizzle 16B slots: byte ^= (row&7)<<4
        const float* Pg = proj_emb + (size_t)t * 16384;
        #pragma unroll
        for (int it = 0; it < 16; ++it) {
            int o = (it * NTHR + tid) * 4;        // f32 index
            float4 v = *(const float4*)(Pg + o);
            int m = o >> 7, c = o & 127;
            unsigned kb = (unsigned)(2 * c) ^ (((unsigned)m & 7u) << 4);
            unsigned lo = (unsigned)f2bf(v.x) | ((unsigned)f2bf(v.y) << 16);
            unsigned hi = (unsigned)f2bf(v.z) | ((unsigned)f2bf(v.w) << 16);
            *(uint2*)((char*)ldsP + (size_t)m * 256 + kb) = make_uint2(lo, hi);
        }
        if (tid < 128) ldsT[tid] = time_emb[(size_t)t * 128 + tid];
    }
    __syncthreads();

    if (has) {
        // groups of 16 consecutive sorted samples; block covers g_id ≡ chunk (mod CPB),
        // wave w takes g_id = chunk + CPB*(w + 4*pass)
        for (int g = off + 16 * (chunk + CPB * wave); g < end; g += 16 * CPB * 4) {
            int p = g + n;
            bool actv = (p < end);
            int sv = sorted[actv ? p : (end - 1)];
            int uidx, pidx;
            if (sv < B) { uidx = pos_u[sv]; pidx = pos_p[sv]; }
            else        { int r = sv - B; uidx = neg_u[r]; pidx = neg_p[r]; }

            // B-fragments: u row -> bf16, lane holds k = kk*32 + q*8 .. +7
            const float* up = user_emb + (size_t)uidx * 128;
            bfx8 ub[4];
            #pragma unroll
            for (int kk = 0; kk < 4; ++kk) {
                const float* usrc = up + kk * 32 + q * 8;
                float4 a = *(const float4*)(usrc);
                float4 b = *(const float4*)(usrc + 4);
                bfx8 f;
                f[0] = (short)f2bf(a.x); f[1] = (short)f2bf(a.y);
                f[2] = (short)f2bf(a.z); f[3] = (short)f2bf(a.w);
                f[4] = (short)f2bf(b.x); f[5] = (short)f2bf(b.y);
                f[6] = (short)f2bf(b.z); f[7] = (short)f2bf(b.w);
                ub[kk] = f;
            }

            f32x4 acc[8];
            #pragma unroll
            for (int mt = 0; mt < 8; ++mt) acc[mt] = (f32x4)(0.f);

            // V = P * U : 8 M-tiles x 4 K-steps
            #pragma unroll
            for (int mt = 0; mt < 8; ++mt) {
                #pragma unroll
                for (int kk = 0; kk < 4; ++kk) {
                    unsigned kb = (unsigned)(kk * 64 + q * 16) ^ (((unsigned)n & 7u) << 4);
                    bfx8 af = *(const bfx8*)((const char*)ldsP + (size_t)(mt * 16 + n) * 256 + kb);
                    acc[mt] = __builtin_amdgcn_mfma_f32_16x16x32_bf16(af, ub[kk], acc[mt], 0, 0, 0);
                }
            }

            // epilogue: score = sum_m (V[m][n] + time[m]) * poi[m]
            // C/D layout: col = lane&15 (sample), row = (lane>>4)*4 + reg
            const float* pp = poi_emb + (size_t)pidx * 128;
            float part = 0.f;
            #pragma unroll
            for (int mt = 0; mt < 8; ++mt) {
                int mo = mt * 16 + q * 4;
                float4 pv = *(const float4*)(pp + mo);
                float4 tv = *(const float4*)(ldsT + mo);
                part += (acc[mt][0] + tv.x) * pv.x;
                part += (acc[mt][1] + tv.y) * pv.y;
                part += (acc[mt][2] + tv.z) * pv.z;
                part += (acc[mt][3] + tv.w) * pv.w;
            }
            part += __shfl_xor(part, 16, 64);
            part += __shfl_xor(part, 32, 64);

            if (actv && q == 0) {
                if (sv < B) out[sv] = softplusf(-part);
                else atomicAdd(&ldsNeg[wave * 16 + ((sv - B) >> shiftB)], softplusf(part));
            }
        }
    }
    __syncthreads();

    // always write (ws is poisoned); empty blocks contribute zeros
    if (tid < NS) {
        float sum = ldsNeg[tid] + ldsNeg[16 + tid] + ldsNeg[32 + tid] + ldsNeg[48 + tid];
        negpart[(size_t)tid * gridN + blockIdx.x] = sum;
    }
}

// ---------------- final neg reduction (one block per ns) ----------------
__global__ void k_reduce(const float* __restrict__ negpart, float* __restrict__ out,
                         int B, int gridN) {
    __shared__ float red[256];
    int ns = blockIdx.x;
    float acc = 0.f;
    for (int r = threadIdx.x; r < gridN; r += 256)
        acc += negpart[(size_t)ns * gridN + r];
    red[threadIdx.x] = acc;
    __syncthreads();
    for (int s2 = 128; s2 > 0; s2 >>= 1) {
        if (threadIdx.x < s2) red[threadIdx.x] += red[threadIdx.x + s2];
        __syncthreads();
    }
    if (threadIdx.x == 0) out[B + ns] = red[0];
}

extern "C" void kernel_launch(void* const* d_in, const int* in_sizes, int n_in,
                              void* d_out, int out_size, void* d_ws, size_t ws_size,
                              hipStream_t stream) {
    const int*   pos_u    = (const int*)d_in[0];
    const int*   pos_t    = (const int*)d_in[1];
    const int*   pos_p    = (const int*)d_in[2];
    const int*   neg_u    = (const int*)d_in[3];
    const int*   neg_t    = (const int*)d_in[4];
    const int*   neg_p    = (const int*)d_in[5];
    const float* user_emb = (const float*)d_in[7];
    const float* poi_emb  = (const float*)d_in[8];
    const float* time_emb = (const float*)d_in[9];
    const float* proj_emb = (const float*)d_in[10];
    float* out = (float*)d_out;

    const int B     = in_sizes[0];           // 4096
    const int NS    = in_sizes[3] / B;       // 10
    const int total = B + NS * B;            // 45056
    const int T     = in_sizes[9] / 128;     // 168 time slots
    const int NB    = (total + 1023) / 1024; // preprocessing blocks (44)

    int shiftB = 0;
    while ((1 << shiftB) < B) shiftB++;      // B = 4096 (pow2)

    const int gridN = T * CPB;               // k_main grid (672)

    // workspace layout
    int* ws_i    = (int*)d_ws;
    int* hcnt    = ws_i;                     // [T*NB]
    int* cbase   = hcnt + T * NB;            // [T*NB]
    int* offsets = cbase + T * NB;           // [T+1]
    int* sorted  = offsets + T + 1;          // [total]
    float* negpart = (float*)(sorted + total);  // [NS][gridN]

    k1_hist<<<NB, 1024, 0, stream>>>(pos_t, neg_t, hcnt, B, total, T, NB);
    k2_scan<<<1, 256, 0, stream>>>(hcnt, cbase, offsets, T, NB);
    k3_scatter<<<NB, 1024, 0, stream>>>(pos_t, neg_t, cbase, sorted, B, total, T, NB);
    k_main<<<gridN, NTHR, 0, stream>>>(pos_u, pos_p, neg_u, neg_p,
                                       user_emb, poi_emb, time_emb, proj_emb,
                                       offsets, sorted, out, negpart,
                                       B, shiftB, NS, gridN);
    k_reduce<<<NS, 256, 0, stream>>>(negpart, out, B, gridN);
}